// Round 6
// baseline (608.371 us; speedup 1.0000x reference)
//
#include <hip/hip_runtime.h>
#include <math.h>

// ---------------------------------------------------------------------------
// GCN link prediction. bf16 node tables + bf16 MFMA, fp32 accumulate.
// Counting-sort CSR (atomic-free). Round-6: fuse agg1+GEMM2 (k_aggmm1, h1
// never hits HBM; rout folded into the LDS tile) and agg2+GEMM3 (k_aggmm2),
// 256-edge k_edge blocks, merged build kernels (9 launches total).
// agg gathers are at their compulsory-miss floor (round-5 analysis).
// ---------------------------------------------------------------------------

#define NBLK 256
#define NBUK 512
#define GRD (NBUK * NBLK)
#define GRT (2 * GRD)

typedef __attribute__((ext_vector_type(8))) short bf16x8;
typedef __attribute__((ext_vector_type(4))) float f32x4;

__device__ __forceinline__ float bl(unsigned u) { return __uint_as_float(u << 16); }
__device__ __forceinline__ float bh(unsigned u) { return __uint_as_float(u & 0xffff0000u); }
__device__ __forceinline__ unsigned short f2bf(float f) {
  unsigned u = __float_as_uint(f);
  return (unsigned short)((u + 0x7fffu + ((u >> 16) & 1u)) >> 16);
}
__device__ __forceinline__ unsigned packbf2(float a, float b) {
  return (unsigned)f2bf(a) | ((unsigned)f2bf(b) << 16);
}

__global__ __launch_bounds__(256) void k_hist(
    const int* __restrict__ src, const int* __restrict__ dst,
    int* __restrict__ grams, int E,
    const float* __restrict__ W1, const float* __restrict__ W2,
    const float* __restrict__ Wp1, const float* __restrict__ Wp2,
    unsigned short* __restrict__ W1t, unsigned short* __restrict__ W2t,
    unsigned short* __restrict__ Wct, unsigned short* __restrict__ Wp2t) {
  __shared__ int hd[NBUK], hs[NBUK];
  int blk = blockIdx.x, t = threadIdx.x;
  {
    int i = blk * 256 + t;
    if (i < 16384) {
      int n = i >> 7, k = i & 127;
      W1t[i] = f2bf(W1[k * 128 + n]);
    } else if (i < 24576) {
      int j = i - 16384; int n = j >> 7, k = j & 127;
      W2t[j] = f2bf(W2[k * 64 + n]);
    } else if (i < 32768) {
      int j = i - 24576; int c = j >> 6, k = j & 63;
      float v = (c < 64) ? Wp1[k * 64 + c] : Wp1[(k + 64) * 64 + (c - 64)];
      Wct[j] = f2bf(v);
    } else if (i < 34816) {
      int j = i - 32768; int n = j >> 6, k = j & 63;
      Wp2t[j] = f2bf(Wp2[k * 32 + n]);
    }
  }
  for (int k = t; k < NBUK; k += 256) { hd[k] = 0; hs[k] = 0; }
  __syncthreads();
  int chunk = (E + NBLK - 1) / NBLK;
  int start = blk * chunk, end = min(E, start + chunk);
  for (int i = start + t; i < end; i += 256) {
    atomicAdd(&hd[dst[i] >> 8], 1);
    atomicAdd(&hs[src[i] >> 8], 1);
  }
  __syncthreads();
  for (int k = t; k < NBUK; k += 256) {
    grams[k * NBLK + blk] = hd[k];
    grams[GRD + k * NBLK + blk] = hs[k];
  }
}

__global__ __launch_bounds__(256) void k_gscan1(const int* __restrict__ g,
                                                int* __restrict__ bsum) {
  __shared__ int lds[256];
  int b = blockIdx.x, t = threadIdx.x;
  int base = b * 1024 + t * 4;
  int s = g[base] + g[base + 1] + g[base + 2] + g[base + 3];
  lds[t] = s; __syncthreads();
  for (int st = 128; st > 0; st >>= 1) {
    if (t < st) lds[t] += lds[t + st];
    __syncthreads();
  }
  if (t == 0) bsum[b] = lds[0];
}

__global__ __launch_bounds__(256) void k_gscan3(int* __restrict__ g,
                                                const int* __restrict__ bsum) {
  __shared__ int lds[256], lds2[256];
  int b = blockIdx.x, t = threadIdx.x;
  int bv = bsum[t];
  lds2[t] = bv; __syncthreads();
  for (int st = 1; st < 256; st <<= 1) {
    int add = (t >= st) ? lds2[t - st] : 0;
    __syncthreads();
    lds2[t] += add;
    __syncthreads();
  }
  int bpref = (b > 0) ? lds2[b - 1] : 0;

  int base = b * 1024 + t * 4;
  int v[4]; int s = 0;
#pragma unroll
  for (int j = 0; j < 4; j++) { v[j] = g[base + j]; s += v[j]; }
  lds[t] = s; __syncthreads();
  int mine = s;
  for (int st = 1; st < 256; st <<= 1) {
    int add = (t >= st) ? lds[t - st] : 0;
    __syncthreads();
    lds[t] += add;
    __syncthreads();
  }
  int excl = lds[t] - mine + bpref;
#pragma unroll
  for (int j = 0; j < 4; j++) { g[base + j] = excl; excl += v[j]; }
}

__global__ __launch_bounds__(256) void k_part(
    const int* __restrict__ src, const int* __restrict__ dst,
    const int* __restrict__ grams, uint2* __restrict__ pdst,
    int* __restrict__ sbuf, int E) {
  __shared__ int curd[NBUK], curs[NBUK];
  int blk = blockIdx.x, t = threadIdx.x;
  for (int k = t; k < NBUK; k += 256) {
    curd[k] = grams[k * NBLK + blk];
    curs[k] = grams[GRD + k * NBLK + blk] - E;
  }
  __syncthreads();
  int chunk = (E + NBLK - 1) / NBLK;
  int start = blk * chunk, end = min(E, start + chunk);
  for (int i = start + t; i < end; i += 256) {
    int s = src[i], d = dst[i];
    int pd = atomicAdd(&curd[d >> 8], 1);
    pdst[pd] = make_uint2((unsigned)s, (unsigned)i | ((unsigned)(d & 255) << 21));
    int ps = atomicAdd(&curs[s >> 8], 1);
    sbuf[ps] = s;
  }
}

__global__ __launch_bounds__(256) void k_dcsr(
    const uint2* __restrict__ pdst, const int* __restrict__ sbuf,
    const int* __restrict__ grams,
    int* __restrict__ adj, int* __restrict__ dnode, int* __restrict__ eidx,
    int* __restrict__ rowst, float* __restrict__ rin, float* __restrict__ rout,
    int N, int E) {
  __shared__ int hist[256], cur[256];
  int b = blockIdx.x, t = threadIdx.x;
  int base = grams[b * 256];
  int end  = grams[b * 256 + 256];
  hist[t] = 0; __syncthreads();
  for (int i = base + t; i < end; i += 256)
    atomicAdd(&hist[(pdst[i].y >> 21) & 255], 1);
  __syncthreads();
  int cnt = hist[t];
  for (int st = 1; st < 256; st <<= 1) {
    int add = (t >= st) ? hist[t - st] : 0;
    __syncthreads();
    hist[t] += add;
    __syncthreads();
  }
  int excl = hist[t] - cnt;
  cur[t] = excl;
  int node = b * 256 + t;
  if (node < N) {
    rowst[node] = base + excl;
    rin[node] = rsqrtf((float)max(cnt, 1));
  }
  __syncthreads();
  for (int i = base + t; i < end; i += 256) {
    uint2 u = pdst[i];
    int lo = (u.y >> 21) & 255;
    int eid = (int)(u.y & 0x1FFFFFu);
    int pos = base + atomicAdd(&cur[lo], 1);
    adj[pos] = (int)u.x;
    dnode[pos] = b * 256 + lo;
    eidx[pos] = eid;
  }
  __syncthreads();
  hist[t] = 0; __syncthreads();
  int sb = grams[GRD + b * 256] - E;
  int se = grams[GRD + b * 256 + 256] - E;
  for (int i = sb + t; i < se; i += 256)
    atomicAdd(&hist[sbuf[i] & 255], 1);
  __syncthreads();
  if (node < N) rout[node] = rsqrtf((float)max(hist[t], 1));
}

__global__ __launch_bounds__(256) void k_gemm1(
    const float* __restrict__ A, const float* __restrict__ scale,
    const unsigned short* __restrict__ Wt, unsigned short* __restrict__ C, int M) {
  __shared__ __attribute__((aligned(16))) unsigned short As[64][136];
  __shared__ __attribute__((aligned(16))) unsigned short Ws[128][136];
  int tid = threadIdx.x;
  int row0 = blockIdx.x * 64;

  for (int i = tid; i < 128 * 16; i += 256) {
    int n = i >> 4, seg = i & 15;
    *(uint4*)&Ws[n][seg * 8] = ((const uint4*)Wt)[i];
  }
  {
    int r = tid >> 2, q = tid & 3;
    int row = row0 + r;
    if (row < M) {
      float sc = scale[row];
      const float4* ap = (const float4*)(A + (size_t)row * 128 + q * 32);
#pragma unroll
      for (int c = 0; c < 4; c++) {
        float4 v0 = ap[2 * c], v1 = ap[2 * c + 1];
        uint4 o;
        o.x = packbf2(v0.x * sc, v0.y * sc);
        o.y = packbf2(v0.z * sc, v0.w * sc);
        o.z = packbf2(v1.x * sc, v1.y * sc);
        o.w = packbf2(v1.z * sc, v1.w * sc);
        *(uint4*)&As[r][q * 32 + c * 8] = o;
      }
    } else {
#pragma unroll
      for (int c = 0; c < 4; c++)
        *(uint4*)&As[r][q * 32 + c * 8] = make_uint4(0, 0, 0, 0);
    }
  }
  __syncthreads();

  int wav = tid >> 6, lane = tid & 63;
  int quad = lane >> 4, lrow = lane & 15;
  int mb = wav * 16;

  bf16x8 af[4];
#pragma unroll
  for (int s = 0; s < 4; s++)
    af[s] = *(const bf16x8*)&As[mb + lrow][s * 32 + quad * 8];

  f32x4 acc[8];
#pragma unroll
  for (int nt = 0; nt < 8; nt++) acc[nt] = (f32x4){0.f, 0.f, 0.f, 0.f};
#pragma unroll
  for (int nt = 0; nt < 8; nt++)
#pragma unroll
    for (int s = 0; s < 4; s++) {
      bf16x8 bf = *(const bf16x8*)&Ws[nt * 16 + lrow][s * 32 + quad * 8];
      acc[nt] = __builtin_amdgcn_mfma_f32_16x16x32_bf16(af[s], bf, acc[nt], 0, 0, 0);
    }
#pragma unroll
  for (int nt = 0; nt < 8; nt++)
#pragma unroll
    for (int reg = 0; reg < 4; reg++) {
      int row = row0 + mb + quad * 4 + reg;
      if (row < M) C[(size_t)row * 128 + nt * 16 + lrow] = f2bf(acc[nt][reg]);
    }
}

// fused agg1 + GEMM2: LDS row = relu(Agg(h0)*rin + b1) * rout; h2p = row @ W2
__global__ __launch_bounds__(256) void k_aggmm1(
    const unsigned short* __restrict__ hin, const int* __restrict__ rowst,
    const int* __restrict__ adj, const float* __restrict__ rin,
    const float* __restrict__ rout, const float* __restrict__ b1,
    const unsigned short* __restrict__ W2t,
    unsigned short* __restrict__ hout, int N, int E) {
  __shared__ __attribute__((aligned(16))) unsigned short As[64][136];
  __shared__ __attribute__((aligned(16))) unsigned short Ws[64][136];
  int t = threadIdx.x;
  int row0 = blockIdx.x * 64;
  int wav = t >> 6, lane = t & 63;

  for (int i = t; i < 64 * 16; i += 256) {
    int n = i >> 4, seg = i & 15;
    *(uint4*)&Ws[n][seg * 8] = ((const uint4*)W2t)[i];
  }

  const unsigned* h2 = (const unsigned*)hin;
  float bx = b1[lane * 2], by = b1[lane * 2 + 1];
#pragma unroll 1
  for (int i2 = 0; i2 < 16; i2++) {
    int r = wav * 16 + i2;
    int node = row0 + r;
    if (node < N) {
      int s0 = rowst[node];
      int e0 = (node + 1 < N) ? rowst[node + 1] : E;
      float ax0 = 0.f, ay0 = 0.f, ax1 = 0.f, ay1 = 0.f;
      int i = s0;
      for (; i + 1 < e0; i += 2) {
        unsigned w0 = h2[(size_t)adj[i] * 64 + lane];
        unsigned w1 = h2[(size_t)adj[i + 1] * 64 + lane];
        ax0 += bl(w0); ay0 += bh(w0);
        ax1 += bl(w1); ay1 += bh(w1);
      }
      if (i < e0) {
        unsigned w0 = h2[(size_t)adj[i] * 64 + lane];
        ax0 += bl(w0); ay0 += bh(w0);
      }
      float rr = rin[node];
      float ro = rout[node];
      float ox = fmaxf(fmaf(ax0 + ax1, rr, bx), 0.f) * ro;
      float oy = fmaxf(fmaf(ay0 + ay1, rr, by), 0.f) * ro;
      *(unsigned*)&As[r][lane * 2] = packbf2(ox, oy);
    } else {
      *(unsigned*)&As[r][lane * 2] = 0;
    }
  }
  __syncthreads();

  int quad = lane >> 4, lrow = lane & 15;
  int mb = wav * 16;
  bf16x8 af[4];
#pragma unroll
  for (int s = 0; s < 4; s++)
    af[s] = *(const bf16x8*)&As[mb + lrow][s * 32 + quad * 8];
  f32x4 acc[4];
#pragma unroll
  for (int nt = 0; nt < 4; nt++) acc[nt] = (f32x4){0.f, 0.f, 0.f, 0.f};
#pragma unroll
  for (int nt = 0; nt < 4; nt++)
#pragma unroll
    for (int s = 0; s < 4; s++) {
      bf16x8 bf = *(const bf16x8*)&Ws[nt * 16 + lrow][s * 32 + quad * 8];
      acc[nt] = __builtin_amdgcn_mfma_f32_16x16x32_bf16(af[s], bf, acc[nt], 0, 0, 0);
    }
#pragma unroll
  for (int nt = 0; nt < 4; nt++)
#pragma unroll
    for (int reg = 0; reg < 4; reg++) {
      int row = row0 + mb + quad * 4 + reg;
      if (row < N) hout[(size_t)row * 64 + nt * 16 + lrow] = f2bf(acc[nt][reg]);
    }
}

// fused agg2 + GEMM3: LDS row = Agg(h2p)*rin + b2; ab = row @ Wc
__global__ __launch_bounds__(256) void k_aggmm2(
    const unsigned short* __restrict__ hin, const int* __restrict__ rowst,
    const int* __restrict__ adj, const float* __restrict__ rin,
    const float* __restrict__ b2, const unsigned short* __restrict__ Wct,
    unsigned short* __restrict__ ab, int N, int E) {
  __shared__ __attribute__((aligned(16))) unsigned short As[64][72];
  __shared__ __attribute__((aligned(16))) unsigned short Ws[128][72];
  int t = threadIdx.x;
  int row0 = blockIdx.x * 64;
  int wav = t >> 6, lane = t & 63;

  for (int i = t; i < 128 * 8; i += 256) {
    int n = i >> 3, seg = i & 7;
    *(uint4*)&Ws[n][seg * 8] = ((const uint4*)Wct)[i];
  }

  const unsigned* h2 = (const unsigned*)hin;
  int half = lane >> 5, fl = lane & 31;
  float bx = b2[fl * 2], by = b2[fl * 2 + 1];
#pragma unroll 1
  for (int i2 = 0; i2 < 16; i2++) {
    int r = wav * 16 + i2;
    int node = row0 + r;
    if (node < N) {
      int s0 = rowst[node];
      int e0 = (node + 1 < N) ? rowst[node + 1] : E;
      float ax0 = 0.f, ay0 = 0.f, ax1 = 0.f, ay1 = 0.f;
      int i = s0 + half;
      for (; i + 2 < e0; i += 4) {
        unsigned w0 = h2[(size_t)adj[i] * 32 + fl];
        unsigned w1 = h2[(size_t)adj[i + 2] * 32 + fl];
        ax0 += bl(w0); ay0 += bh(w0);
        ax1 += bl(w1); ay1 += bh(w1);
      }
      if (i < e0) {
        unsigned w0 = h2[(size_t)adj[i] * 32 + fl];
        ax0 += bl(w0); ay0 += bh(w0);
      }
      float ax = ax0 + ax1, ay = ay0 + ay1;
      ax += __shfl_xor(ax, 32, 64);
      ay += __shfl_xor(ay, 32, 64);
      float rr = rin[node];
      float ox = fmaf(ax, rr, bx);
      float oy = fmaf(ay, rr, by);
      if (half == 0) *(unsigned*)&As[r][fl * 2] = packbf2(ox, oy);
    } else {
      if (half == 0) *(unsigned*)&As[r][fl * 2] = 0;
    }
  }
  __syncthreads();

  int quad = lane >> 4, lrow = lane & 15;
  int mb = wav * 16;
  bf16x8 af[2];
#pragma unroll
  for (int s = 0; s < 2; s++)
    af[s] = *(const bf16x8*)&As[mb + lrow][s * 32 + quad * 8];
  f32x4 acc[8];
#pragma unroll
  for (int nt = 0; nt < 8; nt++) acc[nt] = (f32x4){0.f, 0.f, 0.f, 0.f};
#pragma unroll
  for (int nt = 0; nt < 8; nt++)
#pragma unroll
    for (int s = 0; s < 2; s++) {
      bf16x8 bf = *(const bf16x8*)&Ws[nt * 16 + lrow][s * 32 + quad * 8];
      acc[nt] = __builtin_amdgcn_mfma_f32_16x16x32_bf16(af[s], bf, acc[nt], 0, 0, 0);
    }
#pragma unroll
  for (int nt = 0; nt < 8; nt++)
#pragma unroll
    for (int reg = 0; reg < 4; reg++) {
      int row = row0 + mb + quad * 4 + reg;
      if (row < N) ab[(size_t)row * 128 + nt * 16 + lrow] = f2bf(acc[nt][reg]);
    }
}

__global__ __launch_bounds__(256) void k_edge(
    const unsigned short* __restrict__ ab, const int* __restrict__ adj,
    const int* __restrict__ dnode, const int* __restrict__ eidx,
    const unsigned short* __restrict__ Wp2t, const float* __restrict__ bp1,
    const float* __restrict__ bp2, const float* __restrict__ Wp3,
    const float* __restrict__ bp3, float* __restrict__ out, int E) {
  __shared__ __attribute__((aligned(16))) unsigned short z1s[256][72];
  __shared__ __attribute__((aligned(16))) unsigned short w2t[32][72];
  __shared__ float sb1[64], sb2[32], sw3[32];

  int t = threadIdx.x;
  {
    uint4 v = ((const uint4*)Wp2t)[t];
    int n = t >> 3, seg = t & 7;
    *(uint4*)&w2t[n][seg * 8] = v;
    if (t < 64) sb1[t] = bp1[t];
    else if (t < 96) sb2[t - 64] = bp2[t - 64];
    else if (t < 128) sw3[t - 96] = Wp3[t - 96];
  }
  __syncthreads();

  int p0 = blockIdx.x * 256;
  {
    int p = p0 + t;
    int s = 0, d = 0;
    if (p < E) { s = adj[p]; d = dnode[p]; }
    const uint4* apf = (const uint4*)(ab + (size_t)s * 128);
    const uint4* bpf = (const uint4*)(ab + (size_t)d * 128 + 64);
#pragma unroll
    for (int q = 0; q < 8; q++) {
      uint4 av = apf[q], bv = bpf[q];
      int j = 8 * q;
      float z0 = fmaxf(bl(av.x) + bl(bv.x) + sb1[j + 0], 0.f);
      float z1 = fmaxf(bh(av.x) + bh(bv.x) + sb1[j + 1], 0.f);
      float z2 = fmaxf(bl(av.y) + bl(bv.y) + sb1[j + 2], 0.f);
      float z3 = fmaxf(bh(av.y) + bh(bv.y) + sb1[j + 3], 0.f);
      float z4 = fmaxf(bl(av.z) + bl(bv.z) + sb1[j + 4], 0.f);
      float z5 = fmaxf(bh(av.z) + bh(bv.z) + sb1[j + 5], 0.f);
      float z6 = fmaxf(bl(av.w) + bl(bv.w) + sb1[j + 6], 0.f);
      float z7 = fmaxf(bh(av.w) + bh(bv.w) + sb1[j + 7], 0.f);
      uint4 o;
      o.x = packbf2(z0, z1); o.y = packbf2(z2, z3);
      o.z = packbf2(z4, z5); o.w = packbf2(z6, z7);
      *(uint4*)&z1s[t][j] = o;
    }
  }
  __syncthreads();

  int wav = t >> 6, lane = t & 63;
  int quad = lane >> 4, lrow = lane & 15;

  bf16x8 bfr[2][2];
#pragma unroll
  for (int s = 0; s < 2; s++)
#pragma unroll
    for (int nt = 0; nt < 2; nt++)
      bfr[s][nt] = *(const bf16x8*)&w2t[nt * 16 + lrow][s * 32 + quad * 8];

  float bb0 = sb2[lrow], bb1 = sb2[16 + lrow];
  float w30 = sw3[lrow], w31 = sw3[16 + lrow];
  float b3 = bp3[0];

#pragma unroll
  for (int mt = 0; mt < 4; mt++) {
    int mb = wav * 64 + mt * 16;
    f32x4 acc0 = (f32x4){0.f, 0.f, 0.f, 0.f};
    f32x4 acc1 = (f32x4){0.f, 0.f, 0.f, 0.f};
#pragma unroll
    for (int s = 0; s < 2; s++) {
      bf16x8 a = *(const bf16x8*)&z1s[mb + lrow][s * 32 + quad * 8];
      acc0 = __builtin_amdgcn_mfma_f32_16x16x32_bf16(a, bfr[s][0], acc0, 0, 0, 0);
      acc1 = __builtin_amdgcn_mfma_f32_16x16x32_bf16(a, bfr[s][1], acc1, 0, 0, 0);
    }
    float p2[4];
#pragma unroll
    for (int reg = 0; reg < 4; reg++)
      p2[reg] = fmaxf(acc0[reg] + bb0, 0.f) * w30 +
                fmaxf(acc1[reg] + bb1, 0.f) * w31;
#pragma unroll
    for (int off = 1; off < 16; off <<= 1)
#pragma unroll
      for (int reg = 0; reg < 4; reg++)
        p2[reg] += __shfl_xor(p2[reg], off, 64);
    if (lrow < 4) {
      float score = p2[0];
      if (lrow == 1) score = p2[1];
      if (lrow == 2) score = p2[2];
      if (lrow == 3) score = p2[3];
      score += b3;
      int pp = p0 + mb + quad * 4 + lrow;
      if (pp < E) out[eidx[pp]] = 1.0f / (1.0f + __expf(-score));
    }
  }
}

extern "C" void kernel_launch(void* const* d_in, const int* in_sizes, int n_in,
                              void* d_out, int out_size, void* d_ws, size_t ws_size,
                              hipStream_t stream) {
  const float* x   = (const float*)d_in[0];
  const int*   src = (const int*)d_in[1];
  const int*   dst = (const int*)d_in[2];
  const float* W1  = (const float*)d_in[3];
  const float* b1  = (const float*)d_in[4];
  const float* W2  = (const float*)d_in[5];
  const float* b2  = (const float*)d_in[6];
  const float* Wp1 = (const float*)d_in[7];
  const float* bp1 = (const float*)d_in[8];
  const float* Wp2 = (const float*)d_in[9];
  const float* bp2 = (const float*)d_in[10];
  const float* Wp3 = (const float*)d_in[11];
  const float* bp3 = (const float*)d_in[12];
  float* out = (float*)d_out;

  int N = in_sizes[0] / 128;
  int E = in_sizes[1];

  char* w = (char*)d_ws;
  unsigned short* bufA = (unsigned short*)w;          // aliases pdst+sbuf
  uint2* pdst = (uint2*)w;
  int*   sbuf = (int*)(w + (size_t)E * 8);
  w += (size_t)N * 128 * 2;
  unsigned short* bufB = (unsigned short*)w; w += (size_t)N * 128 * 2;
  int* grams  = (int*)w;    w += (size_t)GRT * sizeof(int);
  int* bsum   = (int*)w;    w += 256 * sizeof(int);
  int* rowst  = (int*)w;    w += (size_t)N * sizeof(int);
  int* adj    = (int*)w;    w += (size_t)E * sizeof(int);
  int* dnode  = (int*)w;    w += (size_t)E * sizeof(int);
  int* eidx   = (int*)w;    w += (size_t)E * sizeof(int);
  float* rin  = (float*)w;  w += (size_t)N * sizeof(float);
  float* rout = (float*)w;  w += (size_t)N * sizeof(float);
  unsigned short* W1t  = (unsigned short*)w; w += 16384 * 2;
  unsigned short* W2t  = (unsigned short*)w; w += 8192 * 2;
  unsigned short* Wct  = (unsigned short*)w; w += 8192 * 2;
  unsigned short* Wp2t = (unsigned short*)w; w += 2048 * 2;

  int nbk = (N + 255) / 256;
  int ngb = (N + 63) / 64;

  k_hist<<<NBLK, 256, 0, stream>>>(src, dst, grams, E, W1, W2, Wp1, Wp2,
                                   W1t, W2t, Wct, Wp2t);
  k_gscan1<<<GRT / 1024, 256, 0, stream>>>(grams, bsum);
  k_gscan3<<<GRT / 1024, 256, 0, stream>>>(grams, bsum);
  k_part<<<NBLK, 256, 0, stream>>>(src, dst, grams, pdst, sbuf, E);
  k_dcsr<<<nbk, 256, 0, stream>>>(pdst, sbuf, grams, adj, dnode, eidx,
                                  rowst, rin, rout, N, E);

  k_gemm1<<<ngb, 256, 0, stream>>>(x, rout, W1t, bufA, N);
  k_aggmm1<<<ngb, 256, 0, stream>>>(bufA, rowst, adj, rin, rout, b1, W2t, bufB, N, E);
  k_aggmm2<<<ngb, 256, 0, stream>>>(bufB, rowst, adj, rin, b2, Wct, bufA, N, E);
  k_edge<<<(E + 255) / 256, 256, 0, stream>>>(bufA, adj, dnode, eidx, Wp2t,
                                              bp1, bp2, Wp3, bp3, out, E);
}

// Round 7
// 433.285 us; speedup vs baseline: 1.4041x; 1.4041x over previous
//
#include <hip/hip_runtime.h>
#include <math.h>

// ---------------------------------------------------------------------------
// GCN link prediction. bf16 node tables + bf16 MFMA, fp32 accumulate.
// Counting-sort CSR (atomic-free). Round-7: REVERT the agg+GEMM fusion
// (round-6 showed fused gathers drop to 908 GB/s vs 2.09 TB/s — barrier +
// low occupancy kills memory-level parallelism). Separate k_agg kernels
// with half-wave-per-edge wide loads (uint2/uint, 2 edges + 2-deep ILP in
// flight per wave). Keep merged build kernels (hist+prep, dcsr+scsr).
// ---------------------------------------------------------------------------

#define NBLK 256
#define NBUK 512
#define GRD (NBUK * NBLK)
#define GRT (2 * GRD)

typedef __attribute__((ext_vector_type(8))) short bf16x8;
typedef __attribute__((ext_vector_type(4))) float f32x4;

__device__ __forceinline__ float bl(unsigned u) { return __uint_as_float(u << 16); }
__device__ __forceinline__ float bh(unsigned u) { return __uint_as_float(u & 0xffff0000u); }
__device__ __forceinline__ unsigned short f2bf(float f) {
  unsigned u = __float_as_uint(f);
  return (unsigned short)((u + 0x7fffu + ((u >> 16) & 1u)) >> 16);
}
__device__ __forceinline__ unsigned packbf2(float a, float b) {
  return (unsigned)f2bf(a) | ((unsigned)f2bf(b) << 16);
}

// ---- CSR build (counting sort) + weight prep --------------------------------

__global__ __launch_bounds__(256) void k_hist(
    const int* __restrict__ src, const int* __restrict__ dst,
    int* __restrict__ grams, int E,
    const float* __restrict__ W1, const float* __restrict__ W2,
    const float* __restrict__ Wp1, const float* __restrict__ Wp2,
    unsigned short* __restrict__ W1t, unsigned short* __restrict__ W2t,
    unsigned short* __restrict__ Wct, unsigned short* __restrict__ Wp2t) {
  __shared__ int hd[NBUK], hs[NBUK];
  int blk = blockIdx.x, t = threadIdx.x;
  {
    int i = blk * 256 + t;
    if (i < 16384) {
      int n = i >> 7, k = i & 127;
      W1t[i] = f2bf(W1[k * 128 + n]);
    } else if (i < 24576) {
      int j = i - 16384; int n = j >> 7, k = j & 127;
      W2t[j] = f2bf(W2[k * 64 + n]);
    } else if (i < 32768) {
      int j = i - 24576; int c = j >> 6, k = j & 63;
      float v = (c < 64) ? Wp1[k * 64 + c] : Wp1[(k + 64) * 64 + (c - 64)];
      Wct[j] = f2bf(v);
    } else if (i < 34816) {
      int j = i - 32768; int n = j >> 6, k = j & 63;
      Wp2t[j] = f2bf(Wp2[k * 32 + n]);
    }
  }
  for (int k = t; k < NBUK; k += 256) { hd[k] = 0; hs[k] = 0; }
  __syncthreads();
  int chunk = (E + NBLK - 1) / NBLK;
  int start = blk * chunk, end = min(E, start + chunk);
  for (int i = start + t; i < end; i += 256) {
    atomicAdd(&hd[dst[i] >> 8], 1);
    atomicAdd(&hs[src[i] >> 8], 1);
  }
  __syncthreads();
  for (int k = t; k < NBUK; k += 256) {
    grams[k * NBLK + blk] = hd[k];
    grams[GRD + k * NBLK + blk] = hs[k];
  }
}

__global__ __launch_bounds__(256) void k_gscan1(const int* __restrict__ g,
                                                int* __restrict__ bsum) {
  __shared__ int lds[256];
  int b = blockIdx.x, t = threadIdx.x;
  int base = b * 1024 + t * 4;
  int s = g[base] + g[base + 1] + g[base + 2] + g[base + 3];
  lds[t] = s; __syncthreads();
  for (int st = 128; st > 0; st >>= 1) {
    if (t < st) lds[t] += lds[t + st];
    __syncthreads();
  }
  if (t == 0) bsum[b] = lds[0];
}

__global__ __launch_bounds__(256) void k_gscan3(int* __restrict__ g,
                                                const int* __restrict__ bsum) {
  __shared__ int lds[256], lds2[256];
  int b = blockIdx.x, t = threadIdx.x;
  int bv = bsum[t];
  lds2[t] = bv; __syncthreads();
  for (int st = 1; st < 256; st <<= 1) {
    int add = (t >= st) ? lds2[t - st] : 0;
    __syncthreads();
    lds2[t] += add;
    __syncthreads();
  }
  int bpref = (b > 0) ? lds2[b - 1] : 0;

  int base = b * 1024 + t * 4;
  int v[4]; int s = 0;
#pragma unroll
  for (int j = 0; j < 4; j++) { v[j] = g[base + j]; s += v[j]; }
  lds[t] = s; __syncthreads();
  int mine = s;
  for (int st = 1; st < 256; st <<= 1) {
    int add = (t >= st) ? lds[t - st] : 0;
    __syncthreads();
    lds[t] += add;
    __syncthreads();
  }
  int excl = lds[t] - mine + bpref;
#pragma unroll
  for (int j = 0; j < 4; j++) { g[base + j] = excl; excl += v[j]; }
}

__global__ __launch_bounds__(256) void k_part(
    const int* __restrict__ src, const int* __restrict__ dst,
    const int* __restrict__ grams, uint2* __restrict__ pdst,
    int* __restrict__ sbuf, int E) {
  __shared__ int curd[NBUK], curs[NBUK];
  int blk = blockIdx.x, t = threadIdx.x;
  for (int k = t; k < NBUK; k += 256) {
    curd[k] = grams[k * NBLK + blk];
    curs[k] = grams[GRD + k * NBLK + blk] - E;
  }
  __syncthreads();
  int chunk = (E + NBLK - 1) / NBLK;
  int start = blk * chunk, end = min(E, start + chunk);
  for (int i = start + t; i < end; i += 256) {
    int s = src[i], d = dst[i];
    int pd = atomicAdd(&curd[d >> 8], 1);
    pdst[pd] = make_uint2((unsigned)s, (unsigned)i | ((unsigned)(d & 255) << 21));
    int ps = atomicAdd(&curs[s >> 8], 1);
    sbuf[ps] = s;
  }
}

__global__ __launch_bounds__(256) void k_dcsr(
    const uint2* __restrict__ pdst, const int* __restrict__ sbuf,
    const int* __restrict__ grams,
    int* __restrict__ adj, int* __restrict__ dnode, int* __restrict__ eidx,
    int* __restrict__ rowst, float* __restrict__ rin, float* __restrict__ rout,
    int N, int E) {
  __shared__ int hist[256], cur[256];
  int b = blockIdx.x, t = threadIdx.x;
  int base = grams[b * 256];
  int end  = grams[b * 256 + 256];
  hist[t] = 0; __syncthreads();
  for (int i = base + t; i < end; i += 256)
    atomicAdd(&hist[(pdst[i].y >> 21) & 255], 1);
  __syncthreads();
  int cnt = hist[t];
  for (int st = 1; st < 256; st <<= 1) {
    int add = (t >= st) ? hist[t - st] : 0;
    __syncthreads();
    hist[t] += add;
    __syncthreads();
  }
  int excl = hist[t] - cnt;
  cur[t] = excl;
  int node = b * 256 + t;
  if (node < N) {
    rowst[node] = base + excl;
    rin[node] = rsqrtf((float)max(cnt, 1));
  }
  __syncthreads();
  for (int i = base + t; i < end; i += 256) {
    uint2 u = pdst[i];
    int lo = (u.y >> 21) & 255;
    int eid = (int)(u.y & 0x1FFFFFu);
    int pos = base + atomicAdd(&cur[lo], 1);
    adj[pos] = (int)u.x;
    dnode[pos] = b * 256 + lo;
    eidx[pos] = eid;
  }
  __syncthreads();
  hist[t] = 0; __syncthreads();
  int sb = grams[GRD + b * 256] - E;
  int se = grams[GRD + b * 256 + 256] - E;
  for (int i = sb + t; i < se; i += 256)
    atomicAdd(&hist[sbuf[i] & 255], 1);
  __syncthreads();
  if (node < N) rout[node] = rsqrtf((float)max(hist[t], 1));
}

// ---- MFMA GEMM: C_bf16[M,BN] = (A[M,K]*scale[M]?) @ W[K,BN], Wt bf16 [BN][K]
template <int K, int BN, bool ABF, bool SC>
__global__ __launch_bounds__(256) void k_gemm(
    const void* __restrict__ Av, const float* __restrict__ scale,
    const unsigned short* __restrict__ Wt, unsigned short* __restrict__ C, int M) {
  constexpr int KP = K + 8;
  __shared__ __attribute__((aligned(16))) unsigned short As[64][KP];
  __shared__ __attribute__((aligned(16))) unsigned short Ws[BN][KP];
  int tid = threadIdx.x;
  int row0 = blockIdx.x * 64;

  for (int i = tid; i < BN * K / 8; i += 256) {
    int n = i / (K / 8), seg = i % (K / 8);
    *(uint4*)&Ws[n][seg * 8] = ((const uint4*)Wt)[i];
  }
  {
    constexpr int CH = K / 4;
    int r = tid >> 2, q = tid & 3;
    int row = row0 + r;
    if (row < M) {
      float sc = SC ? scale[row] : 1.0f;
      if constexpr (!ABF) {
        const float4* ap = (const float4*)((const float*)Av + (size_t)row * K + q * CH);
#pragma unroll
        for (int c = 0; c < CH / 8; c++) {
          float4 v0 = ap[2 * c], v1 = ap[2 * c + 1];
          uint4 o;
          o.x = packbf2(v0.x * sc, v0.y * sc);
          o.y = packbf2(v0.z * sc, v0.w * sc);
          o.z = packbf2(v1.x * sc, v1.y * sc);
          o.w = packbf2(v1.z * sc, v1.w * sc);
          *(uint4*)&As[r][q * CH + c * 8] = o;
        }
      } else {
        const uint4* ap = (const uint4*)((const unsigned short*)Av + (size_t)row * K + q * CH);
#pragma unroll
        for (int c = 0; c < CH / 8; c++) {
          uint4 v = ap[c];
          if constexpr (SC) {
            uint4 o;
            o.x = packbf2(bl(v.x) * sc, bh(v.x) * sc);
            o.y = packbf2(bl(v.y) * sc, bh(v.y) * sc);
            o.z = packbf2(bl(v.z) * sc, bh(v.z) * sc);
            o.w = packbf2(bl(v.w) * sc, bh(v.w) * sc);
            *(uint4*)&As[r][q * CH + c * 8] = o;
          } else {
            *(uint4*)&As[r][q * CH + c * 8] = v;
          }
        }
      }
    } else {
#pragma unroll
      for (int c = 0; c < CH / 8; c++)
        *(uint4*)&As[r][q * CH + c * 8] = make_uint4(0, 0, 0, 0);
    }
  }
  __syncthreads();

  constexpr int KS = K / 32;
  constexpr int NT = BN / 16;
  int wav = tid >> 6, lane = tid & 63;
  int quad = lane >> 4, lrow = lane & 15;
  int mb = wav * 16;

  bf16x8 af[KS];
#pragma unroll
  for (int s = 0; s < KS; s++)
    af[s] = *(const bf16x8*)&As[mb + lrow][s * 32 + quad * 8];

  f32x4 acc[NT];
#pragma unroll
  for (int nt = 0; nt < NT; nt++) acc[nt] = (f32x4){0.f, 0.f, 0.f, 0.f};
#pragma unroll
  for (int nt = 0; nt < NT; nt++) {
#pragma unroll
    for (int s = 0; s < KS; s++) {
      bf16x8 bf = *(const bf16x8*)&Ws[nt * 16 + lrow][s * 32 + quad * 8];
      acc[nt] = __builtin_amdgcn_mfma_f32_16x16x32_bf16(af[s], bf, acc[nt], 0, 0, 0);
    }
  }
#pragma unroll
  for (int nt = 0; nt < NT; nt++) {
#pragma unroll
    for (int reg = 0; reg < 4; reg++) {
      int row = row0 + mb + quad * 4 + reg;
      if (row < M) C[(size_t)row * BN + nt * 16 + lrow] = f2bf(acc[nt][reg]);
    }
  }
}

// ---- aggregation: one wave/node, half-wave per edge, wide loads -------------
// F=128: 32 lanes x uint2 (8B) per edge; F=64: 32 lanes x uint (4B).
// Two edges in flight (halves) x 2-deep unroll = 4 outstanding row loads.
template <int F>
__global__ __launch_bounds__(256) void k_agg(
    const unsigned short* __restrict__ hin, const int* __restrict__ rowst,
    const int* __restrict__ adj, const float* __restrict__ rin,
    const float* __restrict__ bias, unsigned short* __restrict__ hout,
    int N, int E, int do_relu) {
  int node = (blockIdx.x * 256 + threadIdx.x) >> 6;
  int lane = threadIdx.x & 63;
  if (node >= N) return;
  int start = rowst[node];
  int end = (node + 1 < N) ? rowst[node + 1] : E;
  int half = lane >> 5, fl = lane & 31;
  if (F == 128) {
    const uint2* h2 = (const uint2*)hin;  // row = 32 x uint2
    float a0 = 0.f, a1 = 0.f, a2 = 0.f, a3 = 0.f;
    float c0 = 0.f, c1 = 0.f, c2 = 0.f, c3 = 0.f;
    int i = start + half;
    for (; i + 2 < end; i += 4) {
      uint2 w0 = h2[(size_t)adj[i] * 32 + fl];
      uint2 w1 = h2[(size_t)adj[i + 2] * 32 + fl];
      a0 += bl(w0.x); a1 += bh(w0.x); a2 += bl(w0.y); a3 += bh(w0.y);
      c0 += bl(w1.x); c1 += bh(w1.x); c2 += bl(w1.y); c3 += bh(w1.y);
    }
    if (i < end) {
      uint2 w0 = h2[(size_t)adj[i] * 32 + fl];
      a0 += bl(w0.x); a1 += bh(w0.x); a2 += bl(w0.y); a3 += bh(w0.y);
    }
    a0 += c0; a1 += c1; a2 += c2; a3 += c3;
    a0 += __shfl_xor(a0, 32, 64);
    a1 += __shfl_xor(a1, 32, 64);
    a2 += __shfl_xor(a2, 32, 64);
    a3 += __shfl_xor(a3, 32, 64);
    float r = rin[node];
    float o0 = fmaf(a0, r, bias[fl * 4 + 0]);
    float o1 = fmaf(a1, r, bias[fl * 4 + 1]);
    float o2 = fmaf(a2, r, bias[fl * 4 + 2]);
    float o3 = fmaf(a3, r, bias[fl * 4 + 3]);
    if (do_relu) {
      o0 = fmaxf(o0, 0.f); o1 = fmaxf(o1, 0.f);
      o2 = fmaxf(o2, 0.f); o3 = fmaxf(o3, 0.f);
    }
    if (half == 0) {
      uint2 o; o.x = packbf2(o0, o1); o.y = packbf2(o2, o3);
      *(uint2*)((unsigned*)hout + (size_t)node * 64 + fl * 2) = o;
    }
  } else {
    const unsigned* h2 = (const unsigned*)hin;  // row = 32 x uint
    float a0 = 0.f, a1 = 0.f, c0 = 0.f, c1 = 0.f;
    int i = start + half;
    for (; i + 2 < end; i += 4) {
      unsigned w0 = h2[(size_t)adj[i] * 32 + fl];
      unsigned w1 = h2[(size_t)adj[i + 2] * 32 + fl];
      a0 += bl(w0); a1 += bh(w0);
      c0 += bl(w1); c1 += bh(w1);
    }
    if (i < end) {
      unsigned w0 = h2[(size_t)adj[i] * 32 + fl];
      a0 += bl(w0); a1 += bh(w0);
    }
    a0 += c0; a1 += c1;
    a0 += __shfl_xor(a0, 32, 64);
    a1 += __shfl_xor(a1, 32, 64);
    float r = rin[node];
    float o0 = fmaf(a0, r, bias[fl * 2 + 0]);
    float o1 = fmaf(a1, r, bias[fl * 2 + 1]);
    if (do_relu) { o0 = fmaxf(o0, 0.f); o1 = fmaxf(o1, 0.f); }
    if (half == 0)
      ((unsigned*)hout)[(size_t)node * 32 + fl] = packbf2(o0, o1);
  }
}

// ---- per-edge MLP, CSR order, 128 edges/block (round-5 known-good) ----------
__global__ __launch_bounds__(256) void k_edge(
    const unsigned short* __restrict__ ab, const int* __restrict__ adj,
    const int* __restrict__ dnode, const int* __restrict__ eidx,
    const unsigned short* __restrict__ Wp2t, const float* __restrict__ bp1,
    const float* __restrict__ bp2, const float* __restrict__ Wp3,
    const float* __restrict__ bp3, float* __restrict__ out, int E) {
  __shared__ __attribute__((aligned(16))) unsigned short z1s[128][72];
  __shared__ __attribute__((aligned(16))) unsigned short w2t[32][72];
  __shared__ float sb1[64], sb2[32], sw3[32];

  int t = threadIdx.x;
  {
    uint4 v = ((const uint4*)Wp2t)[t];
    int n = t >> 3, seg = t & 7;
    *(uint4*)&w2t[n][seg * 8] = v;
    if (t < 64) sb1[t] = bp1[t];
    else if (t < 96) sb2[t - 64] = bp2[t - 64];
    else if (t < 128) sw3[t - 96] = Wp3[t - 96];
  }
  __syncthreads();

  int p0 = blockIdx.x * 128;
  {
    int m = t >> 1, half = t & 1, p = p0 + m;
    int s = 0, d = 0;
    if (p < E) { s = adj[p]; d = dnode[p]; }
    const uint4* apf = (const uint4*)(ab + (size_t)s * 128 + half * 32);
    const uint4* bpf = (const uint4*)(ab + (size_t)d * 128 + 64 + half * 32);
    int jb = half * 32;
#pragma unroll
    for (int q = 0; q < 4; q++) {
      uint4 av = apf[q], bv = bpf[q];
      int j = jb + 8 * q;
      float z0 = fmaxf(bl(av.x) + bl(bv.x) + sb1[j + 0], 0.f);
      float z1 = fmaxf(bh(av.x) + bh(bv.x) + sb1[j + 1], 0.f);
      float z2 = fmaxf(bl(av.y) + bl(bv.y) + sb1[j + 2], 0.f);
      float z3 = fmaxf(bh(av.y) + bh(bv.y) + sb1[j + 3], 0.f);
      float z4 = fmaxf(bl(av.z) + bl(bv.z) + sb1[j + 4], 0.f);
      float z5 = fmaxf(bh(av.z) + bh(bv.z) + sb1[j + 5], 0.f);
      float z6 = fmaxf(bl(av.w) + bl(bv.w) + sb1[j + 6], 0.f);
      float z7 = fmaxf(bh(av.w) + bh(bv.w) + sb1[j + 7], 0.f);
      uint4 o;
      o.x = packbf2(z0, z1); o.y = packbf2(z2, z3);
      o.z = packbf2(z4, z5); o.w = packbf2(z6, z7);
      *(uint4*)&z1s[m][j] = o;
    }
  }
  __syncthreads();

  int wav = t >> 6, lane = t & 63;
  int quad = lane >> 4, lrow = lane & 15;

  bf16x8 bfr[2][2];
#pragma unroll
  for (int s = 0; s < 2; s++)
#pragma unroll
    for (int nt = 0; nt < 2; nt++)
      bfr[s][nt] = *(const bf16x8*)&w2t[nt * 16 + lrow][s * 32 + quad * 8];

  f32x4 acc[2][2];
#pragma unroll
  for (int mt = 0; mt < 2; mt++)
#pragma unroll
    for (int nt = 0; nt < 2; nt++) acc[mt][nt] = (f32x4){0.f, 0.f, 0.f, 0.f};

#pragma unroll
  for (int mt = 0; mt < 2; mt++) {
    int mb = (wav * 2 + mt) * 16;
#pragma unroll
    for (int s = 0; s < 2; s++) {
      bf16x8 a = *(const bf16x8*)&z1s[mb + lrow][s * 32 + quad * 8];
#pragma unroll
      for (int nt = 0; nt < 2; nt++)
        acc[mt][nt] = __builtin_amdgcn_mfma_f32_16x16x32_bf16(a, bfr[s][nt], acc[mt][nt], 0, 0, 0);
    }
  }

  float bb0 = sb2[lrow], bb1 = sb2[16 + lrow];
  float w30 = sw3[lrow], w31 = sw3[16 + lrow];
  float p2[2][4];
#pragma unroll
  for (int mt = 0; mt < 2; mt++)
#pragma unroll
    for (int reg = 0; reg < 4; reg++)
      p2[mt][reg] = fmaxf(acc[mt][0][reg] + bb0, 0.f) * w30 +
                    fmaxf(acc[mt][1][reg] + bb1, 0.f) * w31;
#pragma unroll
  for (int off = 1; off < 16; off <<= 1) {
#pragma unroll
    for (int mt = 0; mt < 2; mt++)
#pragma unroll
      for (int reg = 0; reg < 4; reg++)
        p2[mt][reg] += __shfl_xor(p2[mt][reg], off, 64);
  }
  if (lrow < 4) {
    float b3 = bp3[0];
#pragma unroll
    for (int mt = 0; mt < 2; mt++) {
      float score = p2[mt][0];
      if (lrow == 1) score = p2[mt][1];
      if (lrow == 2) score = p2[mt][2];
      if (lrow == 3) score = p2[mt][3];
      score += b3;
      int pp = p0 + (wav * 2 + mt) * 16 + quad * 4 + lrow;
      if (pp < E) out[eidx[pp]] = 1.0f / (1.0f + __expf(-score));
    }
  }
}

extern "C" void kernel_launch(void* const* d_in, const int* in_sizes, int n_in,
                              void* d_out, int out_size, void* d_ws, size_t ws_size,
                              hipStream_t stream) {
  const float* x   = (const float*)d_in[0];
  const int*   src = (const int*)d_in[1];
  const int*   dst = (const int*)d_in[2];
  const float* W1  = (const float*)d_in[3];
  const float* b1  = (const float*)d_in[4];
  const float* W2  = (const float*)d_in[5];
  const float* b2  = (const float*)d_in[6];
  const float* Wp1 = (const float*)d_in[7];
  const float* bp1 = (const float*)d_in[8];
  const float* Wp2 = (const float*)d_in[9];
  const float* bp2 = (const float*)d_in[10];
  const float* Wp3 = (const float*)d_in[11];
  const float* bp3 = (const float*)d_in[12];
  float* out = (float*)d_out;

  int N = in_sizes[0] / 128;
  int E = in_sizes[1];

  char* w = (char*)d_ws;
  unsigned short* bufA = (unsigned short*)w;          // aliases pdst+sbuf
  uint2* pdst = (uint2*)w;
  int*   sbuf = (int*)(w + (size_t)E * 8);
  w += (size_t)N * 128 * 2;
  unsigned short* bufB = (unsigned short*)w; w += (size_t)N * 128 * 2;
  int* grams  = (int*)w;    w += (size_t)GRT * sizeof(int);
  int* bsum   = (int*)w;    w += 256 * sizeof(int);
  int* rowst  = (int*)w;    w += (size_t)N * sizeof(int);
  int* adj    = (int*)w;    w += (size_t)E * sizeof(int);
  int* dnode  = (int*)w;    w += (size_t)E * sizeof(int);
  int* eidx   = (int*)w;    w += (size_t)E * sizeof(int);
  float* rin  = (float*)w;  w += (size_t)N * sizeof(float);
  float* rout = (float*)w;  w += (size_t)N * sizeof(float);
  unsigned short* W1t  = (unsigned short*)w; w += 16384 * 2;
  unsigned short* W2t  = (unsigned short*)w; w += 8192 * 2;
  unsigned short* Wct  = (unsigned short*)w; w += 8192 * 2;
  unsigned short* Wp2t = (unsigned short*)w; w += 2048 * 2;

  int nbk = (N + 255) / 256;

  // ---- CSR build + weight prep ----
  k_hist<<<NBLK, 256, 0, stream>>>(src, dst, grams, E, W1, W2, Wp1, Wp2,
                                   W1t, W2t, Wct, Wp2t);
  k_gscan1<<<GRT / 1024, 256, 0, stream>>>(grams, bsum);
  k_gscan3<<<GRT / 1024, 256, 0, stream>>>(grams, bsum);
  k_part<<<NBLK, 256, 0, stream>>>(src, dst, grams, pdst, sbuf, E);
  k_dcsr<<<nbk, 256, 0, stream>>>(pdst, sbuf, grams, adj, dnode, eidx,
                                  rowst, rin, rout, N, E);

  // ---- dense pipeline ----
  // h0 = bf16((x*rout)@W1) -> bufA [N,128]
  k_gemm<128, 128, false, true><<<(N + 63) / 64, 256, 0, stream>>>(x, rout, W1t, bufA, N);
  // h1 = relu(Agg(h0)*rin + b1) -> bufB [N,128]
  k_agg<128><<<(N + 3) / 4, 256, 0, stream>>>(bufA, rowst, adj, rin, b1, bufB, N, E, 1);
  // h2p = bf16((h1*rout)@W2) -> bufA [N,64]
  k_gemm<128, 64, true, true><<<(N + 63) / 64, 256, 0, stream>>>(bufB, rout, W2t, bufA, N);
  // h = Agg(h2p)*rin + b2 -> bufB [N,64]
  k_agg<64><<<(N + 3) / 4, 256, 0, stream>>>(bufA, rowst, adj, rin, b2, bufB, N, E, 0);
  // ab = bf16(h @ Wc) -> bufA [N,128]
  k_gemm<64, 128, true, false><<<(N + 63) / 64, 256, 0, stream>>>(bufB, nullptr, Wct, bufA, N);
  // edge MLP + sigmoid, CSR order, scatter by eidx
  k_edge<<<(E + 127) / 128, 256, 0, stream>>>(bufA, adj, dnode, eidx, Wp2t,
                                              bp1, bp2, Wp3, bp3, out, E);
}

// Round 8
// 378.523 us; speedup vs baseline: 1.6072x; 1.1447x over previous
//
#include <hip/hip_runtime.h>
#include <math.h>

// ---------------------------------------------------------------------------
// GCN link prediction. bf16 node tables + bf16 MFMA, fp32 accumulate.
// Counting-sort CSR (atomic-free, slim: pdst packs (src<<8)|dstlow in 4B,
// sbuf is uchar, no dnode/eidx). Round-8:
//  - k_agg: thread-group-per-node (16/8 thr x uint4 chunk), 4-deep unroll
//    => 16 gather-rows in flight per wave (round-7 k_edge proved 3.7 TB/s
//    is reachable with enough outstanding gathers; old agg had only 4).
//  - k_edge: ORIGINAL edge order, coalesced out[e] writes (round-7 showed
//    153 MB write amplification from the eidx 4B random scatter).
// ---------------------------------------------------------------------------

#define NBLK 256
#define NBUK 512
#define GRD (NBUK * NBLK)
#define GRT (2 * GRD)

typedef __attribute__((ext_vector_type(8))) short bf16x8;
typedef __attribute__((ext_vector_type(4))) float f32x4;

__device__ __forceinline__ float bl(unsigned u) { return __uint_as_float(u << 16); }
__device__ __forceinline__ float bh(unsigned u) { return __uint_as_float(u & 0xffff0000u); }
__device__ __forceinline__ unsigned short f2bf(float f) {
  unsigned u = __float_as_uint(f);
  return (unsigned short)((u + 0x7fffu + ((u >> 16) & 1u)) >> 16);
}
__device__ __forceinline__ unsigned packbf2(float a, float b) {
  return (unsigned)f2bf(a) | ((unsigned)f2bf(b) << 16);
}

// ---- CSR build (counting sort) + weight prep --------------------------------

__global__ __launch_bounds__(256) void k_hist(
    const int* __restrict__ src, const int* __restrict__ dst,
    int* __restrict__ grams, int E,
    const float* __restrict__ W1, const float* __restrict__ W2,
    const float* __restrict__ Wp1, const float* __restrict__ Wp2,
    unsigned short* __restrict__ W1t, unsigned short* __restrict__ W2t,
    unsigned short* __restrict__ Wct, unsigned short* __restrict__ Wp2t) {
  __shared__ int hd[NBUK], hs[NBUK];
  int blk = blockIdx.x, t = threadIdx.x;
  {
    int i = blk * 256 + t;
    if (i < 16384) {
      int n = i >> 7, k = i & 127;
      W1t[i] = f2bf(W1[k * 128 + n]);
    } else if (i < 24576) {
      int j = i - 16384; int n = j >> 7, k = j & 127;
      W2t[j] = f2bf(W2[k * 64 + n]);
    } else if (i < 32768) {
      int j = i - 24576; int c = j >> 6, k = j & 63;
      float v = (c < 64) ? Wp1[k * 64 + c] : Wp1[(k + 64) * 64 + (c - 64)];
      Wct[j] = f2bf(v);
    } else if (i < 34816) {
      int j = i - 32768; int n = j >> 6, k = j & 63;
      Wp2t[j] = f2bf(Wp2[k * 32 + n]);
    }
  }
  for (int k = t; k < NBUK; k += 256) { hd[k] = 0; hs[k] = 0; }
  __syncthreads();
  int chunk = (E + NBLK - 1) / NBLK;
  int start = blk * chunk, end = min(E, start + chunk);
  for (int i = start + t; i < end; i += 256) {
    atomicAdd(&hd[dst[i] >> 8], 1);
    atomicAdd(&hs[src[i] >> 8], 1);
  }
  __syncthreads();
  for (int k = t; k < NBUK; k += 256) {
    grams[k * NBLK + blk] = hd[k];
    grams[GRD + k * NBLK + blk] = hs[k];
  }
}

__global__ __launch_bounds__(256) void k_gscan1(const int* __restrict__ g,
                                                int* __restrict__ bsum) {
  __shared__ int lds[256];
  int b = blockIdx.x, t = threadIdx.x;
  int base = b * 1024 + t * 4;
  int s = g[base] + g[base + 1] + g[base + 2] + g[base + 3];
  lds[t] = s; __syncthreads();
  for (int st = 128; st > 0; st >>= 1) {
    if (t < st) lds[t] += lds[t + st];
    __syncthreads();
  }
  if (t == 0) bsum[b] = lds[0];
}

__global__ __launch_bounds__(256) void k_gscan3(int* __restrict__ g,
                                                const int* __restrict__ bsum) {
  __shared__ int lds[256], lds2[256];
  int b = blockIdx.x, t = threadIdx.x;
  int bv = bsum[t];
  lds2[t] = bv; __syncthreads();
  for (int st = 1; st < 256; st <<= 1) {
    int add = (t >= st) ? lds2[t - st] : 0;
    __syncthreads();
    lds2[t] += add;
    __syncthreads();
  }
  int bpref = (b > 0) ? lds2[b - 1] : 0;

  int base = b * 1024 + t * 4;
  int v[4]; int s = 0;
#pragma unroll
  for (int j = 0; j < 4; j++) { v[j] = g[base + j]; s += v[j]; }
  lds[t] = s; __syncthreads();
  int mine = s;
  for (int st = 1; st < 256; st <<= 1) {
    int add = (t >= st) ? lds[t - st] : 0;
    __syncthreads();
    lds[t] += add;
    __syncthreads();
  }
  int excl = lds[t] - mine + bpref;
#pragma unroll
  for (int j = 0; j < 4; j++) { g[base + j] = excl; excl += v[j]; }
}

__global__ __launch_bounds__(256) void k_part(
    const int* __restrict__ src, const int* __restrict__ dst,
    const int* __restrict__ grams, unsigned* __restrict__ pdst,
    unsigned char* __restrict__ sbuf, int E) {
  __shared__ int curd[NBUK], curs[NBUK];
  int blk = blockIdx.x, t = threadIdx.x;
  for (int k = t; k < NBUK; k += 256) {
    curd[k] = grams[k * NBLK + blk];
    curs[k] = grams[GRD + k * NBLK + blk] - E;
  }
  __syncthreads();
  int chunk = (E + NBLK - 1) / NBLK;
  int start = blk * chunk, end = min(E, start + chunk);
  for (int i = start + t; i < end; i += 256) {
    int s = src[i], d = dst[i];
    int pd = atomicAdd(&curd[d >> 8], 1);
    pdst[pd] = ((unsigned)s << 8) | (unsigned)(d & 255);
    int ps = atomicAdd(&curs[s >> 8], 1);
    sbuf[ps] = (unsigned char)(s & 255);
  }
}

__global__ __launch_bounds__(256) void k_dcsr(
    const unsigned* __restrict__ pdst, const unsigned char* __restrict__ sbuf,
    const int* __restrict__ grams,
    int* __restrict__ adj, int* __restrict__ rowst,
    float* __restrict__ rin, float* __restrict__ rout, int N, int E) {
  __shared__ int hist[256], cur[256];
  int b = blockIdx.x, t = threadIdx.x;
  int base = grams[b * 256];
  int end  = grams[b * 256 + 256];
  hist[t] = 0; __syncthreads();
  for (int i = base + t; i < end; i += 256)
    atomicAdd(&hist[pdst[i] & 255], 1);
  __syncthreads();
  int cnt = hist[t];
  for (int st = 1; st < 256; st <<= 1) {
    int add = (t >= st) ? hist[t - st] : 0;
    __syncthreads();
    hist[t] += add;
    __syncthreads();
  }
  int excl = hist[t] - cnt;
  cur[t] = excl;
  int node = b * 256 + t;
  if (node < N) {
    rowst[node] = base + excl;
    rin[node] = rsqrtf((float)max(cnt, 1));
  }
  __syncthreads();
  for (int i = base + t; i < end; i += 256) {
    unsigned u = pdst[i];
    int pos = base + atomicAdd(&cur[u & 255], 1);
    adj[pos] = (int)(u >> 8);
  }
  __syncthreads();
  hist[t] = 0; __syncthreads();
  int sb = grams[GRD + b * 256] - E;
  int se = grams[GRD + b * 256 + 256] - E;
  for (int i = sb + t; i < se; i += 256)
    atomicAdd(&hist[sbuf[i]], 1);
  __syncthreads();
  if (node < N) rout[node] = rsqrtf((float)max(hist[t], 1));
}

// ---- MFMA GEMM: C_bf16[M,BN] = (A[M,K]*scale[M]?) @ W[K,BN], Wt bf16 [BN][K]
template <int K, int BN, bool ABF, bool SC>
__global__ __launch_bounds__(256) void k_gemm(
    const void* __restrict__ Av, const float* __restrict__ scale,
    const unsigned short* __restrict__ Wt, unsigned short* __restrict__ C, int M) {
  constexpr int KP = K + 8;
  __shared__ __attribute__((aligned(16))) unsigned short As[64][KP];
  __shared__ __attribute__((aligned(16))) unsigned short Ws[BN][KP];
  int tid = threadIdx.x;
  int row0 = blockIdx.x * 64;

  for (int i = tid; i < BN * K / 8; i += 256) {
    int n = i / (K / 8), seg = i % (K / 8);
    *(uint4*)&Ws[n][seg * 8] = ((const uint4*)Wt)[i];
  }
  {
    constexpr int CH = K / 4;
    int r = tid >> 2, q = tid & 3;
    int row = row0 + r;
    if (row < M) {
      float sc = SC ? scale[row] : 1.0f;
      if constexpr (!ABF) {
        const float4* ap = (const float4*)((const float*)Av + (size_t)row * K + q * CH);
#pragma unroll
        for (int c = 0; c < CH / 8; c++) {
          float4 v0 = ap[2 * c], v1 = ap[2 * c + 1];
          uint4 o;
          o.x = packbf2(v0.x * sc, v0.y * sc);
          o.y = packbf2(v0.z * sc, v0.w * sc);
          o.z = packbf2(v1.x * sc, v1.y * sc);
          o.w = packbf2(v1.z * sc, v1.w * sc);
          *(uint4*)&As[r][q * CH + c * 8] = o;
        }
      } else {
        const uint4* ap = (const uint4*)((const unsigned short*)Av + (size_t)row * K + q * CH);
#pragma unroll
        for (int c = 0; c < CH / 8; c++) {
          uint4 v = ap[c];
          if constexpr (SC) {
            uint4 o;
            o.x = packbf2(bl(v.x) * sc, bh(v.x) * sc);
            o.y = packbf2(bl(v.y) * sc, bh(v.y) * sc);
            o.z = packbf2(bl(v.z) * sc, bh(v.z) * sc);
            o.w = packbf2(bl(v.w) * sc, bh(v.w) * sc);
            *(uint4*)&As[r][q * CH + c * 8] = o;
          } else {
            *(uint4*)&As[r][q * CH + c * 8] = v;
          }
        }
      }
    } else {
#pragma unroll
      for (int c = 0; c < CH / 8; c++)
        *(uint4*)&As[r][q * CH + c * 8] = make_uint4(0, 0, 0, 0);
    }
  }
  __syncthreads();

  constexpr int KS = K / 32;
  constexpr int NT = BN / 16;
  int wav = tid >> 6, lane = tid & 63;
  int quad = lane >> 4, lrow = lane & 15;
  int mb = wav * 16;

  bf16x8 af[KS];
#pragma unroll
  for (int s = 0; s < KS; s++)
    af[s] = *(const bf16x8*)&As[mb + lrow][s * 32 + quad * 8];

  f32x4 acc[NT];
#pragma unroll
  for (int nt = 0; nt < NT; nt++) acc[nt] = (f32x4){0.f, 0.f, 0.f, 0.f};
#pragma unroll
  for (int nt = 0; nt < NT; nt++) {
#pragma unroll
    for (int s = 0; s < KS; s++) {
      bf16x8 bf = *(const bf16x8*)&Ws[nt * 16 + lrow][s * 32 + quad * 8];
      acc[nt] = __builtin_amdgcn_mfma_f32_16x16x32_bf16(af[s], bf, acc[nt], 0, 0, 0);
    }
  }
#pragma unroll
  for (int nt = 0; nt < NT; nt++) {
#pragma unroll
    for (int reg = 0; reg < 4; reg++) {
      int row = row0 + mb + quad * 4 + reg;
      if (row < M) C[(size_t)row * BN + nt * 16 + lrow] = f2bf(acc[nt][reg]);
    }
  }
}

// ---- aggregation: TPN threads per node, each owns a uint4 (8 bf16) chunk ----
// 4-deep unroll => per wave (F=128): 4 nodes x 4 rows = 16 gather-rows in
// flight. No LDS, no shuffles, coalesced 256B row reads and uint4 writes.
template <int F>
__global__ __launch_bounds__(256) void k_agg(
    const unsigned short* __restrict__ hin, const int* __restrict__ rowst,
    const int* __restrict__ adj, const float* __restrict__ rin,
    const float* __restrict__ bias, unsigned short* __restrict__ hout,
    int N, int E, int do_relu) {
  constexpr int TPN = F / 8;        // 16 (F=128) or 8 (F=64)
  constexpr int NPB = 256 / TPN;    // 16 or 32 nodes per block
  int node = blockIdx.x * NPB + threadIdx.x / TPN;
  int c = threadIdx.x % TPN;
  if (node >= N) return;
  int start = rowst[node];
  int end = (node + 1 < N) ? rowst[node + 1] : E;
  const uint4* h4 = (const uint4*)hin;  // row = TPN uint4s

  float a[8], b[8];
#pragma unroll
  for (int j = 0; j < 8; j++) { a[j] = 0.f; b[j] = 0.f; }

  int i = start;
  for (; i + 3 < end; i += 4) {
    uint4 w0 = h4[(size_t)adj[i] * TPN + c];
    uint4 w1 = h4[(size_t)adj[i + 1] * TPN + c];
    uint4 w2 = h4[(size_t)adj[i + 2] * TPN + c];
    uint4 w3 = h4[(size_t)adj[i + 3] * TPN + c];
    a[0] += bl(w0.x); a[1] += bh(w0.x); a[2] += bl(w0.y); a[3] += bh(w0.y);
    a[4] += bl(w0.z); a[5] += bh(w0.z); a[6] += bl(w0.w); a[7] += bh(w0.w);
    b[0] += bl(w1.x); b[1] += bh(w1.x); b[2] += bl(w1.y); b[3] += bh(w1.y);
    b[4] += bl(w1.z); b[5] += bh(w1.z); b[6] += bl(w1.w); b[7] += bh(w1.w);
    a[0] += bl(w2.x); a[1] += bh(w2.x); a[2] += bl(w2.y); a[3] += bh(w2.y);
    a[4] += bl(w2.z); a[5] += bh(w2.z); a[6] += bl(w2.w); a[7] += bh(w2.w);
    b[0] += bl(w3.x); b[1] += bh(w3.x); b[2] += bl(w3.y); b[3] += bh(w3.y);
    b[4] += bl(w3.z); b[5] += bh(w3.z); b[6] += bl(w3.w); b[7] += bh(w3.w);
  }
  for (; i < end; i++) {
    uint4 w0 = h4[(size_t)adj[i] * TPN + c];
    a[0] += bl(w0.x); a[1] += bh(w0.x); a[2] += bl(w0.y); a[3] += bh(w0.y);
    a[4] += bl(w0.z); a[5] += bh(w0.z); a[6] += bl(w0.w); a[7] += bh(w0.w);
  }
  float r = rin[node];
  const float4* bp = (const float4*)(bias + c * 8);
  float4 bb0 = bp[0], bb1 = bp[1];
  float o0 = fmaf(a[0] + b[0], r, bb0.x);
  float o1 = fmaf(a[1] + b[1], r, bb0.y);
  float o2 = fmaf(a[2] + b[2], r, bb0.z);
  float o3 = fmaf(a[3] + b[3], r, bb0.w);
  float o4 = fmaf(a[4] + b[4], r, bb1.x);
  float o5 = fmaf(a[5] + b[5], r, bb1.y);
  float o6 = fmaf(a[6] + b[6], r, bb1.z);
  float o7 = fmaf(a[7] + b[7], r, bb1.w);
  if (do_relu) {
    o0 = fmaxf(o0, 0.f); o1 = fmaxf(o1, 0.f); o2 = fmaxf(o2, 0.f);
    o3 = fmaxf(o3, 0.f); o4 = fmaxf(o4, 0.f); o5 = fmaxf(o5, 0.f);
    o6 = fmaxf(o6, 0.f); o7 = fmaxf(o7, 0.f);
  }
  uint4 o;
  o.x = packbf2(o0, o1); o.y = packbf2(o2, o3);
  o.z = packbf2(o4, o5); o.w = packbf2(o6, o7);
  ((uint4*)hout)[(size_t)node * TPN + c] = o;
}

// ---- per-edge MLP, ORIGINAL edge order, coalesced out writes ----------------
__global__ __launch_bounds__(256) void k_edge(
    const unsigned short* __restrict__ ab, const int* __restrict__ src,
    const int* __restrict__ dst,
    const unsigned short* __restrict__ Wp2t, const float* __restrict__ bp1,
    const float* __restrict__ bp2, const float* __restrict__ Wp3,
    const float* __restrict__ bp3, float* __restrict__ out, int E) {
  __shared__ __attribute__((aligned(16))) unsigned short z1s[128][72];
  __shared__ __attribute__((aligned(16))) unsigned short w2t[32][72];
  __shared__ float sb1[64], sb2[32], sw3[32];

  int t = threadIdx.x;
  {
    uint4 v = ((const uint4*)Wp2t)[t];
    int n = t >> 3, seg = t & 7;
    *(uint4*)&w2t[n][seg * 8] = v;
    if (t < 64) sb1[t] = bp1[t];
    else if (t < 96) sb2[t - 64] = bp2[t - 64];
    else if (t < 128) sw3[t - 96] = Wp3[t - 96];
  }
  __syncthreads();

  int p0 = blockIdx.x * 128;
  {
    int m = t >> 1, half = t & 1, p = p0 + m;
    int s = 0, d = 0;
    if (p < E) { s = src[p]; d = dst[p]; }
    const uint4* apf = (const uint4*)(ab + (size_t)s * 128 + half * 32);
    const uint4* bpf = (const uint4*)(ab + (size_t)d * 128 + 64 + half * 32);
    int jb = half * 32;
#pragma unroll
    for (int q = 0; q < 4; q++) {
      uint4 av = apf[q], bv = bpf[q];
      int j = jb + 8 * q;
      float z0 = fmaxf(bl(av.x) + bl(bv.x) + sb1[j + 0], 0.f);
      float z1 = fmaxf(bh(av.x) + bh(bv.x) + sb1[j + 1], 0.f);
      float z2 = fmaxf(bl(av.y) + bl(bv.y) + sb1[j + 2], 0.f);
      float z3 = fmaxf(bh(av.y) + bh(bv.y) + sb1[j + 3], 0.f);
      float z4 = fmaxf(bl(av.z) + bl(bv.z) + sb1[j + 4], 0.f);
      float z5 = fmaxf(bh(av.z) + bh(bv.z) + sb1[j + 5], 0.f);
      float z6 = fmaxf(bl(av.w) + bl(bv.w) + sb1[j + 6], 0.f);
      float z7 = fmaxf(bh(av.w) + bh(bv.w) + sb1[j + 7], 0.f);
      uint4 o;
      o.x = packbf2(z0, z1); o.y = packbf2(z2, z3);
      o.z = packbf2(z4, z5); o.w = packbf2(z6, z7);
      *(uint4*)&z1s[m][j] = o;
    }
  }
  __syncthreads();

  int wav = t >> 6, lane = t & 63;
  int quad = lane >> 4, lrow = lane & 15;

  bf16x8 bfr[2][2];
#pragma unroll
  for (int s = 0; s < 2; s++)
#pragma unroll
    for (int nt = 0; nt < 2; nt++)
      bfr[s][nt] = *(const bf16x8*)&w2t[nt * 16 + lrow][s * 32 + quad * 8];

  f32x4 acc[2][2];
#pragma unroll
  for (int mt = 0; mt < 2; mt++)
#pragma unroll
    for (int nt = 0; nt < 2; nt++) acc[mt][nt] = (f32x4){0.f, 0.f, 0.f, 0.f};

#pragma unroll
  for (int mt = 0; mt < 2; mt++) {
    int mb = (wav * 2 + mt) * 16;
#pragma unroll
    for (int s = 0; s < 2; s++) {
      bf16x8 a = *(const bf16x8*)&z1s[mb + lrow][s * 32 + quad * 8];
#pragma unroll
      for (int nt = 0; nt < 2; nt++)
        acc[mt][nt] = __builtin_amdgcn_mfma_f32_16x16x32_bf16(a, bfr[s][nt], acc[mt][nt], 0, 0, 0);
    }
  }

  float bb0 = sb2[lrow], bb1 = sb2[16 + lrow];
  float w30 = sw3[lrow], w31 = sw3[16 + lrow];
  float p2[2][4];
#pragma unroll
  for (int mt = 0; mt < 2; mt++)
#pragma unroll
    for (int reg = 0; reg < 4; reg++)
      p2[mt][reg] = fmaxf(acc[mt][0][reg] + bb0, 0.f) * w30 +
                    fmaxf(acc[mt][1][reg] + bb1, 0.f) * w31;
#pragma unroll
  for (int off = 1; off < 16; off <<= 1) {
#pragma unroll
    for (int mt = 0; mt < 2; mt++)
#pragma unroll
      for (int reg = 0; reg < 4; reg++)
        p2[mt][reg] += __shfl_xor(p2[mt][reg], off, 64);
  }
  if (lrow < 4) {
    float b3 = bp3[0];
#pragma unroll
    for (int mt = 0; mt < 2; mt++) {
      float score = p2[mt][0];
      if (lrow == 1) score = p2[mt][1];
      if (lrow == 2) score = p2[mt][2];
      if (lrow == 3) score = p2[mt][3];
      score += b3;
      int pp = p0 + (wav * 2 + mt) * 16 + quad * 4 + lrow;
      if (pp < E) out[pp] = 1.0f / (1.0f + __expf(-score));
    }
  }
}

extern "C" void kernel_launch(void* const* d_in, const int* in_sizes, int n_in,
                              void* d_out, int out_size, void* d_ws, size_t ws_size,
                              hipStream_t stream) {
  const float* x   = (const float*)d_in[0];
  const int*   src = (const int*)d_in[1];
  const int*   dst = (const int*)d_in[2];
  const float* W1  = (const float*)d_in[3];
  const float* b1  = (const float*)d_in[4];
  const float* W2  = (const float*)d_in[5];
  const float* b2  = (const float*)d_in[6];
  const float* Wp1 = (const float*)d_in[7];
  const float* bp1 = (const float*)d_in[8];
  const float* Wp2 = (const float*)d_in[9];
  const float* bp2 = (const float*)d_in[10];
  const float* Wp3 = (const float*)d_in[11];
  const float* bp3 = (const float*)d_in[12];
  float* out = (float*)d_out;

  int N = in_sizes[0] / 128;
  int E = in_sizes[1];

  char* w = (char*)d_ws;
  unsigned short* bufA = (unsigned short*)w;          // aliases pdst+sbuf
  unsigned* pdst = (unsigned*)w;                      // E*4 (alias)
  unsigned char* sbuf = (unsigned char*)(w + (size_t)E * 4);  // E*1 (alias)
  w += (size_t)N * 128 * 2;
  unsigned short* bufB = (unsigned short*)w; w += (size_t)N * 128 * 2;
  int* grams  = (int*)w;    w += (size_t)GRT * sizeof(int);
  int* bsum   = (int*)w;    w += 256 * sizeof(int);
  int* rowst  = (int*)w;    w += (size_t)N * sizeof(int);
  int* adj    = (int*)w;    w += (size_t)E * sizeof(int);
  float* rin  = (float*)w;  w += (size_t)N * sizeof(float);
  float* rout = (float*)w;  w += (size_t)N * sizeof(float);
  unsigned short* W1t  = (unsigned short*)w; w += 16384 * 2;
  unsigned short* W2t  = (unsigned short*)w; w += 8192 * 2;
  unsigned short* Wct  = (unsigned short*)w; w += 8192 * 2;
  unsigned short* Wp2t = (unsigned short*)w; w += 2048 * 2;

  int nbk = (N + 255) / 256;

  // ---- CSR build + weight prep ----
  k_hist<<<NBLK, 256, 0, stream>>>(src, dst, grams, E, W1, W2, Wp1, Wp2,
                                   W1t, W2t, Wct, Wp2t);
  k_gscan1<<<GRT / 1024, 256, 0, stream>>>(grams, bsum);
  k_gscan3<<<GRT / 1024, 256, 0, stream>>>(grams, bsum);
  k_part<<<NBLK, 256, 0, stream>>>(src, dst, grams, pdst, sbuf, E);
  k_dcsr<<<nbk, 256, 0, stream>>>(pdst, sbuf, grams, adj, rowst, rin, rout, N, E);

  // ---- dense pipeline ----
  // h0 = bf16((x*rout)@W1) -> bufA [N,128]
  k_gemm<128, 128, false, true><<<(N + 63) / 64, 256, 0, stream>>>(x, rout, W1t, bufA, N);
  // h1 = relu(Agg(h0)*rin + b1) -> bufB [N,128]
  k_agg<128><<<(N + 15) / 16, 256, 0, stream>>>(bufA, rowst, adj, rin, b1, bufB, N, E, 1);
  // h2p = bf16((h1*rout)@W2) -> bufA [N,64]
  k_gemm<128, 64, true, true><<<(N + 63) / 64, 256, 0, stream>>>(bufB, rout, W2t, bufA, N);
  // h = Agg(h2p)*rin + b2 -> bufB [N,64]
  k_agg<64><<<(N + 31) / 32, 256, 0, stream>>>(bufA, rowst, adj, rin, b2, bufB, N, E, 0);
  // ab = bf16(h @ Wc) -> bufA [N,128]
  k_gemm<64, 128, true, false><<<(N + 63) / 64, 256, 0, stream>>>(bufB, nullptr, Wct, bufA, N);
  // edge MLP + sigmoid, original edge order, coalesced out
  k_edge<<<(E + 127) / 128, 256, 0, stream>>>(bufA, src, dst, Wp2t,
                                              bp1, bp2, Wp3, bp3, out, E);
}